// Round 1
// baseline (662.662 us; speedup 1.0000x reference)
//
#include <hip/hip_runtime.h>

#define DIMK 64
#define TBL  4096
#define BNTOT 65536   // B*N = 1024*64

// ws float layout
#define WS_S    0
#define WS_AT   64
#define WS_BQT  (64 + 512)
#define WS_CT   (64 + 1024)
#define WS_C0   (64 + 1024 + 64)
// total 1160 floats = 4640 B

__global__ __launch_bounds__(256) void precompute_kernel(
    const float* __restrict__ strength, const float* __restrict__ str_w,
    const float* __restrict__ str_b,
    const float* __restrict__ q_tbl, const float* __restrict__ k_tbl,
    const float* __restrict__ attn_w1, const float* __restrict__ attn_b1,
    const float* __restrict__ pos_w2, const float* __restrict__ pos_b2,
    const int* __restrict__ embed_id, float* __restrict__ ws)
{
    __shared__ float red[4][64];
    const int t = threadIdx.x;
    const int blk = blockIdx.x;
    const int id = embed_id[0];
    if (blk == 0) {
        // s = strength @ str_w + str_b
        const int d = t & 63, part = t >> 6;
        float acc = 0.f;
        for (int i = part * 128; i < part * 128 + 128; ++i)
            acc += strength[i] * str_w[i * 64 + d];
        red[part][d] = acc;
        __syncthreads();
        if (t < 64)
            ws[WS_S + t] = red[0][t] + red[1][t] + red[2][t] + red[3][t] + str_b[t];
    } else if (blk <= 2) {
        // At[h][j] = sum_d Wk[d][j] * attn_w1[d][h]
        const int h = (blk - 1) * 4 + (t >> 6);
        const int j = t & 63;
        const float* W = k_tbl + (size_t)id * TBL;
        float acc = 0.f;
        for (int d = 0; d < 64; ++d) acc += W[d * 64 + j] * attn_w1[d * 8 + h];
        ws[WS_AT + h * 64 + j] = acc;
    } else if (blk <= 4) {
        // Bqt[h][j] = sum_d Wq[d][j] * attn_w1[d][h]
        const int h = (blk - 3) * 4 + (t >> 6);
        const int j = t & 63;
        const float* W = q_tbl + (size_t)id * TBL;
        float acc = 0.f;
        for (int d = 0; d < 64; ++d) acc += W[d * 64 + j] * attn_w1[d * 8 + h];
        ws[WS_BQT + h * 64 + j] = acc;
    } else {
        if (t < 64) {
            // Ct[h][g] = sum_d pos_w2[g][d] * attn_w1[d][h]
            const int h = t >> 3, g = t & 7;
            float acc = 0.f;
            for (int d = 0; d < 64; ++d) acc += pos_w2[g * 64 + d] * attn_w1[d * 8 + h];
            ws[WS_CT + t] = acc;
        } else if (t < 72) {
            // c0[h] = sum_d pos_b2[d] * attn_w1[d][h] + attn_b1[h]
            const int h = t - 64;
            float acc = attn_b1[h];
            for (int d = 0; d < 64; ++d) acc += pos_b2[d] * attn_w1[d * 8 + h];
            ws[WS_C0 + h] = acc;
        }
    }
}

__global__ __launch_bounds__(256, 2) void attn2d_main(
    const float* __restrict__ q, const float* __restrict__ k,
    const float* __restrict__ pos, const float* __restrict__ v_tbl,
    const float* __restrict__ pos_w1, const float* __restrict__ pos_b1,
    const float* __restrict__ pos_w2, const float* __restrict__ pos_b2,
    const float* __restrict__ attn_w2, const float* __restrict__ attn_b2,
    const float* __restrict__ out_w, const float* __restrict__ out_b,
    const int* __restrict__ mask, const int* __restrict__ embed_id,
    const float* __restrict__ ws, float* __restrict__ out)
{
    __shared__ __align__(16) float At_s[8][68];   // row stride 272B: 16B aligned, banks 4h+4j
    __shared__ __align__(16) float Bqt_s[8][68];
    __shared__ __align__(16) float posb_s[4][8][4];
    __shared__ int   maskb_s[4][8];
    __shared__ __align__(16) float hp_s[4][8][8];
    __shared__ __align__(16) float rhid_s[4][8][8];

    const int tid = threadIdx.x;
    const int lane = tid & 63;
    const int wiv = __builtin_amdgcn_readfirstlane(tid >> 6);  // wave in block, SGPR
    const int vrole = lane >> 3;   // v for (v,h)-mapped phases
    const int hrole = lane & 7;    // h for (v,h)-mapped phases

    // ---- block staging: At/Bqt into LDS ----
    for (int i = tid; i < 512; i += 256) {
        const int h = i >> 6, j = i & 63;
        At_s[h][j]  = ws[WS_AT + i];
        Bqt_s[h][j] = ws[WS_BQT + i];
    }

    // ---- per-lane persistent registers ----
    const int id = embed_id[0];
    float wv[64];    // Wv row `lane`  (vh dot)
    float owc[64];   // out_w column `lane`
    {
        const float* wr = v_tbl + (size_t)id * TBL + lane * 64;
        #pragma unroll
        for (int j = 0; j < 64; ++j) wv[j] = wr[j];
        #pragma unroll
        for (int d = 0; d < 64; ++d) owc[d] = out_w[d * 64 + lane];
    }
    float w2ar[8], pw2r[8], ctr[8], w1pr[4];
    #pragma unroll
    for (int h = 0; h < 8; ++h) w2ar[h] = attn_w2[h * 64 + lane];
    #pragma unroll
    for (int g = 0; g < 8; ++g) pw2r[g] = pos_w2[g * 64 + lane];
    #pragma unroll
    for (int g = 0; g < 8; ++g) ctr[g] = ws[WS_CT + hrole * 8 + g];
    #pragma unroll
    for (int i = 0; i < 4; ++i) w1pr[i] = pos_w1[i * 8 + hrole];
    const float b1pr = pos_b1[hrole];
    const float c0r  = ws[WS_C0 + hrole];
    const float sr   = ws[WS_S + lane];
    const float b2pr = pos_b2[lane];
    const float b2ar = attn_b2[lane];
    const float obr  = out_b[lane];
    __syncthreads();

    const int wave_global = blockIdx.x * 4 + wiv;   // 0..8191

    for (int it = 0; it < 8; ++it) {
        const int bn = wave_global + it * 8192;
        __syncthreads();   // A: prev-iteration readers done before buffer reuse

        // ---- stage pos + mask (per-wave buffers) ----
        if (lane < 32) posb_s[wiv][lane >> 2][lane & 3] = pos[(size_t)bn * 32 + lane];
        if (lane < 8)  maskb_s[wiv][lane] = mask[(size_t)bn * 8 + lane];
        __syncthreads();   // B

        // ---- hp[v][h] = relu(pos[v] . pos_w1[:,h] + pos_b1[h]) ----
        {
            const float4 pp = *(const float4*)&posb_s[wiv][vrole][0];
            float hv = b1pr + pp.x * w1pr[0] + pp.y * w1pr[1]
                            + pp.z * w1pr[2] + pp.w * w1pr[3];
            hp_s[wiv][vrole][hrole] = fmaxf(hv, 0.f);
        }
        __syncthreads();   // C

        // ---- hid[v][h] = k[v].At[h] - q.Bqt[h] + hp[v].Ct[h] + c0[h]; relu ----
        {
            const float* kr = k + ((size_t)bn * 8 + vrole) * 64;  // divergent (v) -> vector loads
            const float* qr = q + (size_t)bn * 64;                // uniform -> s_load
            float acc = c0r;
            #pragma unroll
            for (int jj = 0; jj < 16; ++jj) {
                const float4 kk = *(const float4*)(kr + 4 * jj);
                const float4 aa = *(const float4*)&At_s[hrole][4 * jj];
                const float4 bb = *(const float4*)&Bqt_s[hrole][4 * jj];
                acc += kk.x * aa.x + kk.y * aa.y + kk.z * aa.z + kk.w * aa.w;
                acc -= qr[4 * jj + 0] * bb.x + qr[4 * jj + 1] * bb.y
                     + qr[4 * jj + 2] * bb.z + qr[4 * jj + 3] * bb.w;
            }
            const float4 h0 = *(const float4*)&hp_s[wiv][vrole][0];
            const float4 h1 = *(const float4*)&hp_s[wiv][vrole][4];
            acc += h0.x * ctr[0] + h0.y * ctr[1] + h0.z * ctr[2] + h0.w * ctr[3]
                 + h1.x * ctr[4] + h1.y * ctr[5] + h1.z * ctr[6] + h1.w * ctr[7];
            rhid_s[wiv][vrole][hrole] = fmaxf(acc, 0.f);
        }
        __syncthreads();   // D

        // ---- attn2 + mask + softmax over v (lane = d) ----
        float wgt[8];
        {
            float att[8];
            #pragma unroll
            for (int v = 0; v < 8; ++v) {
                const float4 r0 = *(const float4*)&rhid_s[wiv][v][0];
                const float4 r1 = *(const float4*)&rhid_s[wiv][v][4];
                float a = b2ar
                        + r0.x * w2ar[0] + r0.y * w2ar[1] + r0.z * w2ar[2] + r0.w * w2ar[3]
                        + r1.x * w2ar[4] + r1.y * w2ar[5] + r1.z * w2ar[6] + r1.w * w2ar[7];
                att[v] = (maskb_s[wiv][v] != 0) ? a : -1e9f;
            }
            float m = att[0];
            #pragma unroll
            for (int v = 1; v < 8; ++v) m = fmaxf(m, att[v]);
            float ssum = 0.f;
            #pragma unroll
            for (int v = 0; v < 8; ++v) { wgt[v] = __expf(att[v] - m); ssum += wgt[v]; }
            const float inv = __builtin_amdgcn_rcpf(ssum);
            #pragma unroll
            for (int v = 0; v < 8; ++v) wgt[v] *= inv;
        }

        // ---- x[d] = sum_v wgt[v] * (k[v].Wv[d] + s[d] + p[v][d]) ----
        float xacc = 0.f;
        #pragma unroll 2
        for (int v = 0; v < 8; ++v) {
            const float* kr = k + ((size_t)bn * 8 + v) * 64;  // uniform -> s_load + sgpr-FMA
            const float4 h0 = *(const float4*)&hp_s[wiv][v][0];
            const float4 h1 = *(const float4*)&hp_s[wiv][v][4];
            float vacc = sr + b2pr
                + h0.x * pw2r[0] + h0.y * pw2r[1] + h0.z * pw2r[2] + h0.w * pw2r[3]
                + h1.x * pw2r[4] + h1.y * pw2r[5] + h1.z * pw2r[6] + h1.w * pw2r[7];
            #pragma unroll
            for (int j = 0; j < 64; ++j) vacc += kr[j] * wv[j];
            xacc += wgt[v] * vacc;
        }

        // ---- out[e] = sum_d x[d] * out_w[d][e] + out_b[e], via readlane bcast ----
        float oacc = obr;
        #pragma unroll
        for (int d = 0; d < 64; ++d) {
            const float xd = __int_as_float(
                __builtin_amdgcn_readlane(__float_as_int(xacc), d));
            oacc += xd * owc[d];
        }
        out[(size_t)bn * 64 + lane] = oacc;
    }
}

extern "C" void kernel_launch(void* const* d_in, const int* in_sizes, int n_in,
                              void* d_out, int out_size, void* d_ws, size_t ws_size,
                              hipStream_t stream) {
    const float* q        = (const float*)d_in[0];
    const float* k        = (const float*)d_in[1];
    const float* pos      = (const float*)d_in[2];
    const float* strength = (const float*)d_in[3];
    const float* q_tbl    = (const float*)d_in[4];
    const float* k_tbl    = (const float*)d_in[5];
    const float* v_tbl    = (const float*)d_in[6];
    const float* pos_w1   = (const float*)d_in[7];
    const float* pos_b1   = (const float*)d_in[8];
    const float* pos_w2   = (const float*)d_in[9];
    const float* pos_b2   = (const float*)d_in[10];
    const float* attn_w1  = (const float*)d_in[11];
    const float* attn_b1  = (const float*)d_in[12];
    const float* attn_w2  = (const float*)d_in[13];
    const float* attn_b2  = (const float*)d_in[14];
    const float* out_w    = (const float*)d_in[15];
    const float* out_b    = (const float*)d_in[16];
    const float* str_w    = (const float*)d_in[17];
    const float* str_b    = (const float*)d_in[18];
    const int*   mask     = (const int*)d_in[19];
    const int*   embed    = (const int*)d_in[20];
    float* ws  = (float*)d_ws;
    float* out = (float*)d_out;

    hipLaunchKernelGGL(precompute_kernel, dim3(6), dim3(256), 0, stream,
                       strength, str_w, str_b, q_tbl, k_tbl, attn_w1, attn_b1,
                       pos_w2, pos_b2, embed, ws);
    hipLaunchKernelGGL(attn2d_main, dim3(2048), dim3(256), 0, stream,
                       q, k, pos, v_tbl, pos_w1, pos_b1, pos_w2, pos_b2,
                       attn_w2, attn_b2, out_w, out_b, mask, embed, ws, out);
}

// Round 2
// 288.833 us; speedup vs baseline: 2.2943x; 2.2943x over previous
//
#include <hip/hip_runtime.h>

#define TBL 4096

// ws float layout (produced by precompute_kernel)
#define WS_S    0
#define WS_AT   64
#define WS_BQT  (64 + 512)
#define WS_CT   (64 + 1024)
#define WS_C0   (64 + 1024 + 64)

typedef __attribute__((ext_vector_type(8))) short bf16x8;
typedef __attribute__((ext_vector_type(4))) float f32x4;

__device__ inline short f2bf(float f) {
    union { float f; unsigned u; } v; v.f = f;
    unsigned r = v.u + 0x7fffu + ((v.u >> 16) & 1u);
    return (short)(r >> 16);
}

__device__ inline bf16x8 pack8(const float* x) {
    bf16x8 r;
    #pragma unroll
    for (int i = 0; i < 8; ++i) r[i] = f2bf(x[i]);
    return r;
}

__device__ inline bf16x8 loadpack(const float* p) {
    float4 a = *(const float4*)p;
    float4 b = *(const float4*)(p + 4);
    float t[8] = {a.x, a.y, a.z, a.w, b.x, b.y, b.z, b.w};
    return pack8(t);
}

__device__ inline bf16x8 loadpackneg(const float* p) {
    float4 a = *(const float4*)p;
    float4 b = *(const float4*)(p + 4);
    float t[8] = {-a.x, -a.y, -a.z, -a.w, -b.x, -b.y, -b.z, -b.w};
    return pack8(t);
}

__global__ __launch_bounds__(256) void precompute_kernel(
    const float* __restrict__ strength, const float* __restrict__ str_w,
    const float* __restrict__ str_b,
    const float* __restrict__ q_tbl, const float* __restrict__ k_tbl,
    const float* __restrict__ attn_w1, const float* __restrict__ attn_b1,
    const float* __restrict__ pos_w2, const float* __restrict__ pos_b2,
    const int* __restrict__ embed_id, float* __restrict__ ws)
{
    __shared__ float red[4][64];
    const int t = threadIdx.x;
    const int blk = blockIdx.x;
    const int id = embed_id[0];
    if (blk == 0) {
        const int d = t & 63, part = t >> 6;
        float acc = 0.f;
        for (int i = part * 128; i < part * 128 + 128; ++i)
            acc += strength[i] * str_w[i * 64 + d];
        red[part][d] = acc;
        __syncthreads();
        if (t < 64)
            ws[WS_S + t] = red[0][t] + red[1][t] + red[2][t] + red[3][t] + str_b[t];
    } else if (blk <= 2) {
        const int h = (blk - 1) * 4 + (t >> 6);
        const int j = t & 63;
        const float* W = k_tbl + (size_t)id * TBL;
        float acc = 0.f;
        for (int d = 0; d < 64; ++d) acc += W[d * 64 + j] * attn_w1[d * 8 + h];
        ws[WS_AT + h * 64 + j] = acc;
    } else if (blk <= 4) {
        const int h = (blk - 3) * 4 + (t >> 6);
        const int j = t & 63;
        const float* W = q_tbl + (size_t)id * TBL;
        float acc = 0.f;
        for (int d = 0; d < 64; ++d) acc += W[d * 64 + j] * attn_w1[d * 8 + h];
        ws[WS_BQT + h * 64 + j] = acc;
    } else {
        if (t < 64) {
            const int h = t >> 3, g = t & 7;
            float acc = 0.f;
            for (int d = 0; d < 64; ++d) acc += pos_w2[g * 64 + d] * attn_w1[d * 8 + h];
            ws[WS_CT + t] = acc;
        } else if (t < 72) {
            const int h = t - 64;
            float acc = attn_b1[h];
            for (int d = 0; d < 64; ++d) acc += pos_b2[d] * attn_w1[d * 8 + h];
            ws[WS_C0 + h] = acc;
        }
    }
}

// One wave handles 8 bn (4 pairs of 2). All LDS buffers are PER-WAVE -> no
// __syncthreads anywhere in this kernel (wave-internal lgkmcnt ordering only).
__global__ __launch_bounds__(256, 3) void attn2d_main(
    const float* __restrict__ q, const float* __restrict__ k,
    const float* __restrict__ pos, const float* __restrict__ v_tbl,
    const float* __restrict__ pos_w1, const float* __restrict__ pos_b1,
    const float* __restrict__ pos_w2, const float* __restrict__ pos_b2,
    const float* __restrict__ attn_w2, const float* __restrict__ attn_b2,
    const float* __restrict__ out_w, const float* __restrict__ out_b,
    const int* __restrict__ mask, const int* __restrict__ embed_id,
    const float* __restrict__ ws, float* __restrict__ out)
{
    // per-wave LDS (strides chosen for <=2-way bank access everywhere)
    __shared__ float vh_lds[4][16 * 68];   // vh C-tiles, stride 68
    __shared__ float x_lds[4][16 * 68];    // x rows (8 valid), stride 68
    __shared__ float rhid_lds[4][16 * 12]; // relu(hid), stride 12 (float4-aligned)
    __shared__ float hp_lds[4][16 * 8];    // hp rows, stride 8

    const int tid  = threadIdx.x;
    const int lane = tid & 63;
    const int wiv  = __builtin_amdgcn_readfirstlane(tid >> 6);
    const int q4   = lane >> 4;    // quad
    const int col  = lane & 15;    // MFMA col / A-row index

    float* vh_w = vh_lds[wiv];
    float* x_w  = x_lds[wiv];
    float* rh_w = rhid_lds[wiv];
    float* hp_w = hp_lds[wiv];

    const int wid = blockIdx.x * 4 + wiv;      // 0..8191
    const int id  = embed_id[0];

    // ---- persistent B-fragments ----
    // VH: B[k=j][n=d] = Wv[n][j]  (vh = k . Wv^T)
    bf16x8 Bv[4][2];
    #pragma unroll
    for (int t = 0; t < 4; ++t)
        #pragma unroll
        for (int c = 0; c < 2; ++c)
            Bv[t][c] = loadpack(v_tbl + (size_t)id * TBL +
                                (t * 16 + col) * 64 + c * 32 + q4 * 8);
    // HID (K=128 concat): chunks 0-1 = At[n][j], chunks 2-3 = -Bqt[n][j]; n>=8 -> 0
    bf16x8 Bh[4];
    {
        bf16x8 z{};
        #pragma unroll
        for (int c = 0; c < 2; ++c)
            Bh[c] = (col < 8) ? loadpack(ws + WS_AT + col * 64 + c * 32 + q4 * 8) : z;
        #pragma unroll
        for (int c = 0; c < 2; ++c)
            Bh[2 + c] = (col < 8) ? loadpackneg(ws + WS_BQT + col * 64 + c * 32 + q4 * 8) : z;
    }
    // hp contribution: B[k=g][n=h] = Ct[n][g], valid only quad0 (k<8), n<8
    bf16x8 Bct{};
    if (q4 == 0 && col < 8) Bct = loadpack(ws + WS_CT + col * 8);

    // ---- per-lane constants ----
    float w2ar[8], pw2r[8];
    #pragma unroll
    for (int h = 0; h < 8; ++h) w2ar[h] = attn_w2[h * 64 + lane];
    #pragma unroll
    for (int g = 0; g < 8; ++g) pw2r[g] = pos_w2[g * 64 + lane];
    const float sr   = ws[WS_S + lane];
    const float b2pr = pos_b2[lane];
    const float b2ar = attn_b2[lane];
    const float c0r  = (col < 8) ? ws[WS_C0 + col] : 0.f;

    #pragma unroll
    for (int it = 0; it < 4; ++it) {
        const int pair = wid * 4 + it;     // uniform per wave
        const int bn0  = pair * 2;

        // ---- A fragments: k rows (16) and broadcast q rows, f32 -> bf16 ----
        bf16x8 Ak[2], Aq[2];
        #pragma unroll
        for (int c = 0; c < 2; ++c)
            Ak[c] = loadpack(k + ((size_t)pair * 16 + col) * 64 + c * 32 + q4 * 8);
        #pragma unroll
        for (int c = 0; c < 2; ++c)
            Aq[c] = loadpack(q + (size_t)(bn0 + (col >> 3)) * 64 + c * 32 + q4 * 8);

        // ---- hp = relu(pos . pos_w1 + b1), rows on lanes 0-15 ----
        bf16x8 Ahp{};
        if (lane < 16) {
            float4 pp = *(const float4*)(pos + ((size_t)pair * 16 + lane) * 4);
            float hv[8];
            #pragma unroll
            for (int g = 0; g < 8; ++g)
                hv[g] = fmaxf(pos_b1[g] + pp.x * pos_w1[g] + pp.y * pos_w1[8 + g] +
                              pp.z * pos_w1[16 + g] + pp.w * pos_w1[24 + g], 0.f);
            *(float4*)&hp_w[lane * 8]     = make_float4(hv[0], hv[1], hv[2], hv[3]);
            *(float4*)&hp_w[lane * 8 + 4] = make_float4(hv[4], hv[5], hv[6], hv[7]);
            Ahp = pack8(hv);
        }

        // ---- HID: acc[16x16] = k.At - q.Bqt + hp.Ct  (cols 0-7 valid) ----
        f32x4 acch = {0.f, 0.f, 0.f, 0.f};
        acch = __builtin_amdgcn_mfma_f32_16x16x32_bf16(Ak[0], Bh[0], acch, 0, 0, 0);
        acch = __builtin_amdgcn_mfma_f32_16x16x32_bf16(Ak[1], Bh[1], acch, 0, 0, 0);
        acch = __builtin_amdgcn_mfma_f32_16x16x32_bf16(Aq[0], Bh[2], acch, 0, 0, 0);
        acch = __builtin_amdgcn_mfma_f32_16x16x32_bf16(Aq[1], Bh[3], acch, 0, 0, 0);
        acch = __builtin_amdgcn_mfma_f32_16x16x32_bf16(Ahp,   Bct,   acch, 0, 0, 0);
        if (col < 8) {
            #pragma unroll
            for (int r = 0; r < 4; ++r)
                rh_w[(q4 * 4 + r) * 12 + col] = fmaxf(acch[r] + c0r, 0.f);
        }

        // ---- VH: [16 x 64] = k . Wv^T ----
        #pragma unroll
        for (int t = 0; t < 4; ++t) {
            f32x4 a = {0.f, 0.f, 0.f, 0.f};
            a = __builtin_amdgcn_mfma_f32_16x16x32_bf16(Ak[0], Bv[t][0], a, 0, 0, 0);
            a = __builtin_amdgcn_mfma_f32_16x16x32_bf16(Ak[1], Bv[t][1], a, 0, 0, 0);
            #pragma unroll
            for (int r = 0; r < 4; ++r)
                vh_w[(q4 * 4 + r) * 68 + t * 16 + col] = a[r];
        }

        // ---- per-bn: logits (f32) + masked softmax + x accumulation ----
        #pragma unroll
        for (int bnp = 0; bnp < 2; ++bnp) {
            const int rb = bnp * 8;
            float att[8];
            #pragma unroll
            for (int v = 0; v < 8; ++v) {
                const float* rr = &rh_w[(rb + v) * 12];
                float4 r0 = *(const float4*)rr;
                float4 r1 = *(const float4*)(rr + 4);
                float a = b2ar
                        + r0.x * w2ar[0] + r0.y * w2ar[1] + r0.z * w2ar[2] + r0.w * w2ar[3]
                        + r1.x * w2ar[4] + r1.y * w2ar[5] + r1.z * w2ar[6] + r1.w * w2ar[7];
                att[v] = (mask[(size_t)(bn0 + bnp) * 8 + v] != 0) ? a : -1e9f;
            }
            float m = att[0];
            #pragma unroll
            for (int v = 1; v < 8; ++v) m = fmaxf(m, att[v]);
            float wgt[8], ssum = 0.f;
            #pragma unroll
            for (int v = 0; v < 8; ++v) { wgt[v] = __expf(att[v] - m); ssum += wgt[v]; }
            const float inv = __builtin_amdgcn_rcpf(ssum);
            float xacc = 0.f;
            #pragma unroll
            for (int v = 0; v < 8; ++v) {
                const float* hr = &hp_w[(rb + v) * 8];
                float4 h0 = *(const float4*)hr;
                float4 h1 = *(const float4*)(hr + 4);
                float pv = sr + b2pr
                         + h0.x * pw2r[0] + h0.y * pw2r[1] + h0.z * pw2r[2] + h0.w * pw2r[3]
                         + h1.x * pw2r[4] + h1.y * pw2r[5] + h1.z * pw2r[6] + h1.w * pw2r[7];
                xacc += (wgt[v] * inv) * (vh_w[(rb + v) * 68 + lane] + pv);
            }
            x_w[(it * 2 + bnp) * 68 + lane] = xacc;
        }
    }

    // ---- OUT: out[8 x 64] = x . out_w + out_b, batched over the wave's 8 bn ----
    bf16x8 Ax[2];
    #pragma unroll
    for (int c = 0; c < 2; ++c)
        Ax[c] = loadpack(&x_w[col * 68 + c * 32 + q4 * 8]);   // rows 8-15 garbage, discarded
    #pragma unroll
    for (int t = 0; t < 4; ++t) {
        // B[k=d][n=e] = out_w[d*64 + e]
        bf16x8 Bo0, Bo1;
        {
            float t0[8], t1[8];
            #pragma unroll
            for (int jj = 0; jj < 8; ++jj) {
                t0[jj] = out_w[(q4 * 8 + jj) * 64 + t * 16 + col];
                t1[jj] = out_w[(32 + q4 * 8 + jj) * 64 + t * 16 + col];
            }
            Bo0 = pack8(t0); Bo1 = pack8(t1);
        }
        f32x4 a = {0.f, 0.f, 0.f, 0.f};
        a = __builtin_amdgcn_mfma_f32_16x16x32_bf16(Ax[0], Bo0, a, 0, 0, 0);
        a = __builtin_amdgcn_mfma_f32_16x16x32_bf16(Ax[1], Bo1, a, 0, 0, 0);
        const float ob = out_b[t * 16 + col];
        #pragma unroll
        for (int r = 0; r < 4; ++r) {
            const int row = q4 * 4 + r;
            if (row < 8)
                out[((size_t)wid * 8 + row) * 64 + t * 16 + col] = a[r] + ob;
        }
    }
}

extern "C" void kernel_launch(void* const* d_in, const int* in_sizes, int n_in,
                              void* d_out, int out_size, void* d_ws, size_t ws_size,
                              hipStream_t stream) {
    const float* q        = (const float*)d_in[0];
    const float* k        = (const float*)d_in[1];
    const float* pos      = (const float*)d_in[2];
    const float* strength = (const float*)d_in[3];
    const float* q_tbl    = (const float*)d_in[4];
    const float* k_tbl    = (const float*)d_in[5];
    const float* v_tbl    = (const float*)d_in[6];
    const float* pos_w1   = (const float*)d_in[7];
    const float* pos_b1   = (const float*)d_in[8];
    const float* pos_w2   = (const float*)d_in[9];
    const float* pos_b2   = (const float*)d_in[10];
    const float* attn_w1  = (const float*)d_in[11];
    const float* attn_b1  = (const float*)d_in[12];
    const float* attn_w2  = (const float*)d_in[13];
    const float* attn_b2  = (const float*)d_in[14];
    const float* out_w    = (const float*)d_in[15];
    const float* out_b    = (const float*)d_in[16];
    const float* str_w    = (const float*)d_in[17];
    const float* str_b    = (const float*)d_in[18];
    const int*   mask     = (const int*)d_in[19];
    const int*   embed    = (const int*)d_in[20];
    float* ws  = (float*)d_ws;
    float* out = (float*)d_out;

    hipLaunchKernelGGL(precompute_kernel, dim3(6), dim3(256), 0, stream,
                       strength, str_w, str_b, q_tbl, k_tbl, attn_w1, attn_b1,
                       pos_w2, pos_b2, embed, ws);
    hipLaunchKernelGGL(attn2d_main, dim3(2048), dim3(256), 0, stream,
                       q, k, pos, v_tbl, pos_w1, pos_b1, pos_w2, pos_b2,
                       attn_w2, attn_b2, out_w, out_b, mask, embed, ws, out);
}